// Round 5
// baseline (372.625 us; speedup 1.0000x reference)
//
#include <hip/hip_runtime.h>
#include <math.h>

#define EPS 1e-8f
#define KT 32
#define KC1 2
#define HBLK 64          // histogram/scatter blocks
#define NRANGE 8         // d-range buckets (D=1024 -> 128 d each)
#define DLOC 128         // d per range
#define PARTCAP 81920    // per-range sorted capacity = SUBN*EPERB (counts ~62.5k)
#define SUBN 64          // agg subchunks per range
#define EPERB 1280       // PARTCAP / SUBN (edges per agg block)
#define EPERW 320        // EPERB / 4 waves (= 5 batches of 64)

// ---------------------------------------------------------------------------
// K0: row norms. Blocks [0,S): rinv[s] = 1/(||S_s||+eps).
//     Blocks [S, S+B): Hs[b,:] = H[b,:]/(||H_b||+eps), gscale[b]=0.005*||G_b||
// ---------------------------------------------------------------------------
__global__ void k_norms(const float* __restrict__ Sg, const float* __restrict__ Hg,
                        const float* __restrict__ Gg, float* __restrict__ rinv,
                        float* __restrict__ Hs, float* __restrict__ gscale,
                        int Srows, int Fdim, int Bdim) {
    __shared__ float wsum[4];
    __shared__ float wsum2[4];
    __shared__ float bc0;
    int row = blockIdx.x;
    int tid = threadIdx.x;
    int lane = tid & 63, wv = tid >> 6;

    if (row < Srows) {
        const float* p = Sg + (size_t)row * Fdim;
        float acc = 0.f;
        for (int i = tid; i < Fdim; i += 256) { float v = p[i]; acc += v * v; }
        for (int off = 32; off > 0; off >>= 1) acc += __shfl_down(acc, off, 64);
        if (lane == 0) wsum[wv] = acc;
        __syncthreads();
        if (tid == 0) {
            float t = wsum[0] + wsum[1] + wsum[2] + wsum[3];
            rinv[row] = 1.0f / (sqrtf(t) + EPS);
        }
    } else {
        int b = row - Srows;
        if (b >= Bdim) return;
        const float* ph = Hg + (size_t)b * Fdim;
        const float* pg = Gg + (size_t)b * Fdim;
        float ah = 0.f, ag = 0.f;
        for (int i = tid; i < Fdim; i += 256) {
            float h = ph[i]; ah += h * h;
            float g = pg[i]; ag += g * g;
        }
        for (int off = 32; off > 0; off >>= 1) {
            ah += __shfl_down(ah, off, 64);
            ag += __shfl_down(ag, off, 64);
        }
        if (lane == 0) { wsum[wv] = ah; wsum2[wv] = ag; }
        __syncthreads();
        if (tid == 0) {
            float th = wsum[0] + wsum[1] + wsum[2] + wsum[3];
            float tg = wsum2[0] + wsum2[1] + wsum2[2] + wsum2[3];
            bc0 = 1.0f / (sqrtf(th) + EPS);
            gscale[b] = 0.005f * sqrtf(tg);
        }
        __syncthreads();
        float hn = bc0;
        float* dst = Hs + (size_t)b * Fdim;
        for (int i = tid; i < Fdim; i += 256) dst[i] = ph[i] * hn;
    }
}

// ---------------------------------------------------------------------------
// K1: GEMM1  Pt_part[kc][s][b] = rinv[s] * sum_{k in chunk kc} Hs[b,k]*Sg[s,k]
// ---------------------------------------------------------------------------
__global__ __launch_bounds__(256) void k_gemm1(
        const float* __restrict__ Hs, const float* __restrict__ Sg,
        const float* __restrict__ rinv, float* __restrict__ Pt_part,
        int Srows, int Fdim, int kchunk) {
    __shared__ float lA[KT][68];   // [k][b]
    __shared__ float lB[KT][36];   // [k][s]
    int tid = threadIdx.x;
    int tx = tid & 15;          // b: 4 each
    int ty = tid >> 4;          // s: 2 each
    int s0 = blockIdx.x * 32;
    int kb = blockIdx.y * kchunk;

    float4 acc0 = {0.f, 0.f, 0.f, 0.f};
    float4 acc1 = {0.f, 0.f, 0.f, 0.f};

    for (int kt = 0; kt < kchunk; kt += KT) {
        #pragma unroll
        for (int i = 0; i < 8; i++) {
            int idx = tid + i * 256;
            int c = idx & 31, r = idx >> 5;
            lA[c][r] = Hs[(size_t)r * Fdim + kb + kt + c];
        }
        #pragma unroll
        for (int i = 0; i < 4; i++) {
            int idx = tid + i * 256;
            int c = idx & 31, r = idx >> 5;
            lB[c][r] = Sg[(size_t)(s0 + r) * Fdim + kb + kt + c];
        }
        __syncthreads();
        #pragma unroll
        for (int k = 0; k < KT; k++) {
            float4 hv = *(const float4*)&lA[k][tx * 4];
            float2 sv = *(const float2*)&lB[k][ty * 2];
            acc0.x += sv.x * hv.x; acc0.y += sv.x * hv.y;
            acc0.z += sv.x * hv.z; acc0.w += sv.x * hv.w;
            acc1.x += sv.y * hv.x; acc1.y += sv.y * hv.y;
            acc1.z += sv.y * hv.z; acc1.w += sv.y * hv.w;
        }
        __syncthreads();
    }
    int sa = s0 + ty * 2;
    float r0 = rinv[sa], r1 = rinv[sa + 1];
    float4 o0, o1;
    o0.x = acc0.x * r0; o0.y = acc0.y * r0; o0.z = acc0.z * r0; o0.w = acc0.w * r0;
    o1.x = acc1.x * r1; o1.y = acc1.y * r1; o1.z = acc1.z * r1; o1.w = acc1.w * r1;
    size_t base = (size_t)blockIdx.y * Srows;
    *(float4*)&Pt_part[(base + sa) * 64 + tx * 4]     = o0;
    *(float4*)&Pt_part[(base + sa + 1) * 64 + tx * 4] = o1;
}

__global__ void k_combine(const float* __restrict__ Pp, float* __restrict__ Pt, int n) {
    int i = blockIdx.x * 256 + threadIdx.x;
    if (i >= n / 4) return;
    const float4* a = (const float4*)Pp;
    const float4* b = (const float4*)(Pp + n);
    float4 x = a[i], y = b[i];
    x.x += y.x; x.y += y.y; x.z += y.z; x.w += y.w;
    ((float4*)Pt)[i] = x;
}

// ---------------------------------------------------------------------------
// K2: histogram pass. Per-block: count edges per d-range (cnt[blk][8]) and
// colsum partials via LDS (pcs[blk][1024]).
// ---------------------------------------------------------------------------
__global__ __launch_bounds__(256) void k_hist(
        const int* __restrict__ ed, const float* __restrict__ ew,
        int* __restrict__ cnt, float* __restrict__ pcs, int E, int Dd) {
    __shared__ float cw[1024];
    __shared__ int lc[NRANGE];
    int tid = threadIdx.x;
    for (int i = tid; i < Dd; i += 256) cw[i] = 0.f;
    if (tid < NRANGE) lc[tid] = 0;
    __syncthreads();
    int per = (E + HBLK - 1) / HBLK;
    int e0 = blockIdx.x * per, e1 = min(e0 + per, E);
    int myc[NRANGE];
    #pragma unroll
    for (int r = 0; r < NRANGE; r++) myc[r] = 0;
    for (int e = e0 + tid; e < e1; e += 256) {
        int d = ed[e];
        float w = ew[e];
        atomicAdd(&cw[d], w);
        int r = d >> 7;
        #pragma unroll
        for (int rr = 0; rr < NRANGE; rr++) myc[rr] += (r == rr) ? 1 : 0;
    }
    #pragma unroll
    for (int r = 0; r < NRANGE; r++)
        if (myc[r]) atomicAdd(&lc[r], myc[r]);
    __syncthreads();
    if (tid < NRANGE) cnt[blockIdx.x * NRANGE + tid] = lc[tid];
    for (int i = tid; i < Dd; i += 256) pcs[(size_t)blockIdx.x * Dd + i] = cw[i];
}

// offsets: off[c][r] = r*PARTCAP + sum_{c'<c} cnt[c'][r]
__global__ void k_prefix(const int* __restrict__ cnt, int* __restrict__ off) {
    __shared__ int sc[HBLK * NRANGE];
    int tid = threadIdx.x;
    for (int i = tid; i < HBLK * NRANGE; i += 256) sc[i] = cnt[i];
    __syncthreads();
    if (tid < NRANGE) {
        int run = tid * PARTCAP;
        for (int c = 0; c < HBLK; c++) {
            int v = sc[c * NRANGE + tid];
            sc[c * NRANGE + tid] = run;
            run += v;
        }
    }
    __syncthreads();
    for (int i = tid; i < HBLK * NRANGE; i += 256) off[i] = sc[i];
}

// ---------------------------------------------------------------------------
// K3: bucket scatter: edges -> range partitions. Each block writes 8
// contiguous runs (per-block reserved slots) -> coalesced-ish.
// meta = s | (dloc<<16); pads (memset 0) contribute w=0.
// ---------------------------------------------------------------------------
__global__ __launch_bounds__(256) void k_bscatter(
        const int* __restrict__ es, const int* __restrict__ ed,
        const float* __restrict__ ew, const int* __restrict__ off,
        int* __restrict__ sm, float* __restrict__ sw, int E) {
    __shared__ int loff[NRANGE];
    int tid = threadIdx.x;
    if (tid < NRANGE) loff[tid] = off[blockIdx.x * NRANGE + tid];
    __syncthreads();
    int per = (E + HBLK - 1) / HBLK;
    int e0 = blockIdx.x * per, e1 = min(e0 + per, E);
    for (int e = e0 + tid; e < e1; e += 256) {
        int s = es[e], d = ed[e];
        float w = ew[e];
        int r = d >> 7, dl = d & (DLOC - 1);
        int pos = atomicAdd(&loff[r], 1);
        if (pos < (r + 1) * PARTCAP) {
            sm[pos] = s | (dl << 16);
            sw[pos] = w;
        }
    }
}

// colsum[d] = sum_blk pcs[blk][d]
__global__ void k_colsum(const float* __restrict__ pcs, float* __restrict__ colsum,
                         int Dd) {
    int d = blockIdx.x * 256 + threadIdx.x;
    if (d >= Dd) return;
    float s = 0.f;
    #pragma unroll 8
    for (int c = 0; c < HBLK; c++) s += pcs[(size_t)c * Dd + d];
    colsum[d] = s;
}

// ---------------------------------------------------------------------------
// K4: aggregation over sorted edges. Block (c, r): 1280 edges of range r.
// lane = b. Per edge: readlane-broadcast (s,dloc,w), coalesced 256B row read
// Pt[s][0..63], conflict-free LDS atomic into bins[dloc][lane].
// 8-deep load pipeline; all loop bounds static (pads are w=0).
// ---------------------------------------------------------------------------
__global__ __launch_bounds__(256) void k_agg2(
        const float* __restrict__ Pt, const int* __restrict__ sm,
        const float* __restrict__ sw, float* __restrict__ part2) {
    __shared__ float bins[DLOC * 64];   // 32 KB
    int tid = threadIdx.x, lane = tid & 63, wv = tid >> 6;
    int c = blockIdx.x, r = blockIdx.y;
    for (int i = tid; i < DLOC * 64; i += 256) bins[i] = 0.f;
    __syncthreads();

    int base = r * PARTCAP + c * EPERB + wv * EPERW;
    for (int it = 0; it < EPERW / 64; it++) {      // 5 batches of 64 edges
        int mv  = sm[base + it * 64 + lane];
        int wvi = __float_as_int(sw[base + it * 64 + lane]);
        #pragma unroll
        for (int jj = 0; jj < 64; jj += 8) {
            float q[8], wj[8];
            int dl[8];
            #pragma unroll
            for (int k = 0; k < 8; k++) {
                int m = __builtin_amdgcn_readlane(mv, jj + k);
                wj[k] = __int_as_float(__builtin_amdgcn_readlane(wvi, jj + k));
                dl[k] = m >> 16;
                q[k] = Pt[(size_t)(m & 0xFFFF) * 64 + lane];
            }
            #pragma unroll
            for (int k = 0; k < 8; k++)
                atomicAdd(&bins[dl[k] * 64 + lane], wj[k] * q[k]);
        }
    }
    __syncthreads();
    float* dst = part2 + ((size_t)r * SUBN + c) * (DLOC * 64);
    for (int i = tid; i < DLOC * 64; i += 256) dst[i] = bins[i];
}

// ---------------------------------------------------------------------------
// K5: reduce part2 over subchunks: red[r*DLOC+dloc][b] = sum_c part2[r][c][dloc][b]
// grid (NRANGE, DLOC/4), 4 waves/block, wave -> one dloc, lane = b.
// ---------------------------------------------------------------------------
__global__ __launch_bounds__(256) void k_epi1(const float* __restrict__ part2,
                                              float* __restrict__ red) {
    int tid = threadIdx.x, lane = tid & 63, wv = tid >> 6;
    int r = blockIdx.x;
    int dloc = blockIdx.y * 4 + wv;
    float acc = 0.f;
    const float* src = part2 + (size_t)r * SUBN * (DLOC * 64) + dloc * 64 + lane;
    #pragma unroll 8
    for (int c = 0; c < SUBN; c++)
        acc += src[(size_t)c * (DLOC * 64)];
    red[((size_t)r * DLOC + dloc) * 64 + lane] = acc;
}

// ---------------------------------------------------------------------------
// K6: finalize + transpose: out[b][d] = gscale[b]*(red[d][b] + colsum[d])
// ---------------------------------------------------------------------------
__global__ __launch_bounds__(256) void k_epi2(const float* __restrict__ red,
        const float* __restrict__ colsum, const float* __restrict__ gscale,
        float* __restrict__ out, int Dd) {
    __shared__ float tile[64][65];
    int tid = threadIdx.x;
    int dbase = blockIdx.x * 64;
    #pragma unroll
    for (int i = 0; i < 16; i++) {
        int idx = tid + i * 256;
        int dl = idx >> 6, b = idx & 63;
        tile[dl][b] = red[(size_t)(dbase + dl) * 64 + b] + colsum[dbase + dl];
    }
    __syncthreads();
    #pragma unroll
    for (int i = 0; i < 16; i++) {
        int idx = tid + i * 256;
        int b = idx >> 6, dl = idx & 63;
        out[(size_t)b * Dd + dbase + dl] = gscale[b] * tile[dl][b];
    }
}

extern "C" void kernel_launch(void* const* d_in, const int* in_sizes, int n_in,
                              void* d_out, int out_size, void* d_ws, size_t ws_size,
                              hipStream_t stream) {
    const float* H  = (const float*)d_in[0];
    const float* G  = (const float*)d_in[1];
    const float* Sg = (const float*)d_in[2];
    const float* ew = (const float*)d_in[3];
    const int*   ed = (const int*)d_in[4];
    const int*   es = (const int*)d_in[5];

    const int B = 64;
    const int F = in_sizes[0] / B;        // 512
    const int S = in_sizes[2] / F;        // 8192
    const int E = in_sizes[3];            // 500000
    const int D = out_size / B;           // 1024
    float* out = (float*)d_out;

    // workspace layout (4-byte elems); every buffer fully written before read
    float* ws = (float*)d_ws;
    size_t off = 0;
    float* rinv    = ws + off; off += (size_t)S;                 // 8192
    float* Hs      = ws + off; off += (size_t)B * F;             // 32768
    float* gscale  = ws + off; off += 256;
    float* colsum  = ws + off; off += (size_t)D;
    float* Pt_part = ws + off; off += (size_t)KC1 * S * B;       // 1.05M
    float* Pt      = ws + off; off += (size_t)S * B;             // 524288
    int*   cnt     = (int*)(ws + off); off += HBLK * NRANGE;     // 512
    int*   offb    = (int*)(ws + off); off += HBLK * NRANGE;     // 512
    float* pcs     = ws + off; off += (size_t)HBLK * D;          // 65536
    int*   sm      = (int*)(ws + off); off += (size_t)NRANGE * PARTCAP;  // 655360
    float* sw      = ws + off; off += (size_t)NRANGE * PARTCAP;          // 655360 (adjacent to sm)
    float* part2   = ws + off; off += (size_t)NRANGE * SUBN * DLOC * 64; // 4.19M
    float* red     = ws + off; off += (size_t)D * 64;            // 65536

    // zero sorted arrays (pads must be w=0); sm & sw adjacent -> one memset
    hipMemsetAsync(sm, 0, (size_t)2 * NRANGE * PARTCAP * 4, stream);

    k_norms<<<S + B, 256, 0, stream>>>(Sg, H, G, rinv, Hs, gscale, S, F, B);
    dim3 g1(S / 32, KC1);
    k_gemm1<<<g1, 256, 0, stream>>>(Hs, Sg, rinv, Pt_part, S, F, F / KC1);
    int nPt = S * B;
    k_combine<<<(nPt / 4 + 255) / 256, 256, 0, stream>>>(Pt_part, Pt, nPt);
    k_hist<<<HBLK, 256, 0, stream>>>(ed, ew, cnt, pcs, E, D);
    k_prefix<<<1, 256, 0, stream>>>(cnt, offb);
    k_bscatter<<<HBLK, 256, 0, stream>>>(es, ed, ew, offb, sm, sw, E);
    k_colsum<<<(D + 255) / 256, 256, 0, stream>>>(pcs, colsum, D);
    dim3 ga(SUBN, NRANGE);
    k_agg2<<<ga, 256, 0, stream>>>(Pt, sm, sw, part2);
    dim3 ge1(NRANGE, DLOC / 4);
    k_epi1<<<ge1, 256, 0, stream>>>(part2, red);
    k_epi2<<<D / 64, 256, 0, stream>>>(red, colsum, gscale, out, D);
}

// Round 6
// 164.677 us; speedup vs baseline: 2.2628x; 2.2628x over previous
//
#include <hip/hip_runtime.h>
#include <math.h>

#define EPS 1e-8f
#define KT 32
#define KC1 2
#define SCAT 256     // scatter blocks (pcs partials)
#define NS2 64       // gemm2 split-K chunks

// ---------------------------------------------------------------------------
// K0: row norms. Blocks [0,S): rinv[s] = 1/(||S_s||+eps).
//     Blocks [S, S+B): Hs[b,:] = H[b,:]/(||H_b||+eps), gscale[b]=0.005*||G_b||
// ---------------------------------------------------------------------------
__global__ void k_norms(const float* __restrict__ Sg, const float* __restrict__ Hg,
                        const float* __restrict__ Gg, float* __restrict__ rinv,
                        float* __restrict__ Hs, float* __restrict__ gscale,
                        int Srows, int Fdim, int Bdim) {
    __shared__ float wsum[4];
    __shared__ float wsum2[4];
    __shared__ float bc0;
    int row = blockIdx.x;
    int tid = threadIdx.x;
    int lane = tid & 63, wv = tid >> 6;

    if (row < Srows) {
        const float* p = Sg + (size_t)row * Fdim;
        float acc = 0.f;
        for (int i = tid; i < Fdim; i += 256) { float v = p[i]; acc += v * v; }
        for (int off = 32; off > 0; off >>= 1) acc += __shfl_down(acc, off, 64);
        if (lane == 0) wsum[wv] = acc;
        __syncthreads();
        if (tid == 0) {
            float t = wsum[0] + wsum[1] + wsum[2] + wsum[3];
            rinv[row] = 1.0f / (sqrtf(t) + EPS);
        }
    } else {
        int b = row - Srows;
        if (b >= Bdim) return;
        const float* ph = Hg + (size_t)b * Fdim;
        const float* pg = Gg + (size_t)b * Fdim;
        float ah = 0.f, ag = 0.f;
        for (int i = tid; i < Fdim; i += 256) {
            float h = ph[i]; ah += h * h;
            float g = pg[i]; ag += g * g;
        }
        for (int off = 32; off > 0; off >>= 1) {
            ah += __shfl_down(ah, off, 64);
            ag += __shfl_down(ag, off, 64);
        }
        if (lane == 0) { wsum[wv] = ah; wsum2[wv] = ag; }
        __syncthreads();
        if (tid == 0) {
            float th = wsum[0] + wsum[1] + wsum[2] + wsum[3];
            float tg = wsum2[0] + wsum2[1] + wsum2[2] + wsum2[3];
            bc0 = 1.0f / (sqrtf(th) + EPS);
            gscale[b] = 0.005f * sqrtf(tg);
        }
        __syncthreads();
        float hn = bc0;
        float* dst = Hs + (size_t)b * Fdim;
        for (int i = tid; i < Fdim; i += 256) dst[i] = ph[i] * hn;
    }
}

// ---------------------------------------------------------------------------
// K1: edge scatter. W[s,d] += w (global atomics, addresses spread over 33 MB).
//     colsum partials via per-block LDS histogram -> pcs[block][D].
// ---------------------------------------------------------------------------
__global__ __launch_bounds__(256) void k_scatter(
        const float* __restrict__ ew, const int* __restrict__ ed,
        const int* __restrict__ es, float* __restrict__ W,
        float* __restrict__ pcs, int E, int Dd) {
    __shared__ float bins[1024];
    int tid = threadIdx.x;
    for (int i = tid; i < Dd; i += 256) bins[i] = 0.f;
    __syncthreads();
    int stride = gridDim.x * 256;
    for (int e = blockIdx.x * 256 + tid; e < E; e += stride) {
        int s = es[e];
        int d = ed[e];
        float w = ew[e];
        atomicAdd(&W[(size_t)s * Dd + d], w);
        atomicAdd(&bins[d], w);
    }
    __syncthreads();
    float* dst = pcs + (size_t)blockIdx.x * Dd;
    for (int i = tid; i < Dd; i += 256) dst[i] = bins[i];
}

// colsum[d] = sum_blk pcs[blk][d]
__global__ void k_colsum(const float* __restrict__ pcs, float* __restrict__ colsum,
                         int Dd) {
    int d = blockIdx.x * 256 + threadIdx.x;
    if (d >= Dd) return;
    float s = 0.f;
    #pragma unroll 8
    for (int c = 0; c < SCAT; c++) s += pcs[(size_t)c * Dd + d];
    colsum[d] = s;
}

// ---------------------------------------------------------------------------
// K2: GEMM1  Pt_part[kc][s][b] = rinv[s] * sum_{k in chunk kc} Hs[b,k]*Sg[s,k]
// Tile 64b x 32s, KT=32, split-K KC1=2. Grid (S/32, KC1) = 512 blocks.
// s-major coalesced float4 stores. (Proven in R5 run.)
// ---------------------------------------------------------------------------
__global__ __launch_bounds__(256) void k_gemm1(
        const float* __restrict__ Hs, const float* __restrict__ Sg,
        const float* __restrict__ rinv, float* __restrict__ Pt_part,
        int Srows, int Fdim, int kchunk) {
    __shared__ float lA[KT][68];   // [k][b]
    __shared__ float lB[KT][36];   // [k][s]
    int tid = threadIdx.x;
    int tx = tid & 15;          // b: 4 each
    int ty = tid >> 4;          // s: 2 each
    int s0 = blockIdx.x * 32;
    int kb = blockIdx.y * kchunk;

    float4 acc0 = {0.f, 0.f, 0.f, 0.f};
    float4 acc1 = {0.f, 0.f, 0.f, 0.f};

    for (int kt = 0; kt < kchunk; kt += KT) {
        #pragma unroll
        for (int i = 0; i < 8; i++) {
            int idx = tid + i * 256;
            int c = idx & 31, r = idx >> 5;
            lA[c][r] = Hs[(size_t)r * Fdim + kb + kt + c];
        }
        #pragma unroll
        for (int i = 0; i < 4; i++) {
            int idx = tid + i * 256;
            int c = idx & 31, r = idx >> 5;
            lB[c][r] = Sg[(size_t)(s0 + r) * Fdim + kb + kt + c];
        }
        __syncthreads();
        #pragma unroll
        for (int k = 0; k < KT; k++) {
            float4 hv = *(const float4*)&lA[k][tx * 4];
            float2 sv = *(const float2*)&lB[k][ty * 2];
            acc0.x += sv.x * hv.x; acc0.y += sv.x * hv.y;
            acc0.z += sv.x * hv.z; acc0.w += sv.x * hv.w;
            acc1.x += sv.y * hv.x; acc1.y += sv.y * hv.y;
            acc1.z += sv.y * hv.z; acc1.w += sv.y * hv.w;
        }
        __syncthreads();
    }
    int sa = s0 + ty * 2;
    float r0 = rinv[sa], r1 = rinv[sa + 1];
    float4 o0, o1;
    o0.x = acc0.x * r0; o0.y = acc0.y * r0; o0.z = acc0.z * r0; o0.w = acc0.w * r0;
    o1.x = acc1.x * r1; o1.y = acc1.y * r1; o1.z = acc1.z * r1; o1.w = acc1.w * r1;
    size_t base = (size_t)blockIdx.y * Srows;
    *(float4*)&Pt_part[(base + sa) * 64 + tx * 4]     = o0;
    *(float4*)&Pt_part[(base + sa + 1) * 64 + tx * 4] = o1;
}

// ---------------------------------------------------------------------------
// K3: GEMM2  part[kc][b][d] = sum_{k in chunk kc} P'[b,k] * W[k,d]
// P' staged from s-major Pt_part, summing both split-K halves on the fly.
// Tile 64b x 64d, KT=32. Grid (D/64, NS2) = 1024 blocks = 4 waves/SIMD.
// ---------------------------------------------------------------------------
__global__ __launch_bounds__(256) void k_gemm2(
        const float* __restrict__ Pt_part, const float* __restrict__ W,
        float* __restrict__ part, int Srows, int Dd) {
    __shared__ float lA[KT][64];    // [k][b]
    __shared__ float lB[KT][64];    // [k][d]
    int tid = threadIdx.x;
    int tx = tid & 15;   // d: 4 each
    int ty = tid >> 4;   // b: 4 each
    int d0 = blockIdx.x * 64;
    int kchunk = Srows / NS2;          // 128
    int kb = blockIdx.y * kchunk;
    size_t half = (size_t)Srows * 64;

    float4 acc[4];
    #pragma unroll
    for (int j = 0; j < 4; j++) { acc[j].x = acc[j].y = acc[j].z = acc[j].w = 0.f; }

    for (int kt = 0; kt < kchunk; kt += KT) {
        #pragma unroll
        for (int i = 0; i < 8; i++) {          // 32k x 64b
            int idx = tid + i * 256;
            int r = idx & 63, c = idx >> 6;    // r=b, c=k
            size_t src = (size_t)(kb + kt + c) * 64 + r;
            lA[c][r] = Pt_part[src] + Pt_part[half + src];
        }
        #pragma unroll
        for (int i = 0; i < 8; i++) {          // 32k x 64d
            int idx = tid + i * 256;
            int c = idx & 63, r = idx >> 6;    // c=d, r=k
            lB[r][c] = W[(size_t)(kb + kt + r) * Dd + d0 + c];
        }
        __syncthreads();
        #pragma unroll
        for (int k = 0; k < KT; k++) {
            float4 av = *(const float4*)&lA[k][ty * 4];
            float4 bv = *(const float4*)&lB[k][tx * 4];
            acc[0].x += av.x * bv.x; acc[0].y += av.x * bv.y; acc[0].z += av.x * bv.z; acc[0].w += av.x * bv.w;
            acc[1].x += av.y * bv.x; acc[1].y += av.y * bv.y; acc[1].z += av.y * bv.z; acc[1].w += av.y * bv.w;
            acc[2].x += av.z * bv.x; acc[2].y += av.z * bv.y; acc[2].z += av.z * bv.z; acc[2].w += av.z * bv.w;
            acc[3].x += av.w * bv.x; acc[3].y += av.w * bv.y; acc[3].z += av.w * bv.z; acc[3].w += av.w * bv.w;
        }
        __syncthreads();
    }
    #pragma unroll
    for (int j = 0; j < 4; j++) {
        int b = ty * 4 + j;
        *(float4*)&part[((size_t)blockIdx.y * 64 + b) * Dd + d0 + tx * 4] = acc[j];
    }
}

// ---------------------------------------------------------------------------
// K4: epilogue  out[b,d] = gscale[b] * (sum_kc part[kc][b][d] + colsum[d])
// ---------------------------------------------------------------------------
__global__ void k_epi(const float* __restrict__ part, const float* __restrict__ colsum,
                      const float* __restrict__ gscale, float* __restrict__ out,
                      int Dd, int Bdim) {
    int idx = blockIdx.x * 256 + threadIdx.x;
    if (idx >= Bdim * Dd) return;
    int b = idx / Dd;
    int d = idx - b * Dd;
    float s = 0.f;
    #pragma unroll 8
    for (int kc = 0; kc < NS2; kc++)
        s += part[((size_t)kc * Bdim + b) * Dd + d];
    out[idx] = gscale[b] * (s + colsum[d]);
}

extern "C" void kernel_launch(void* const* d_in, const int* in_sizes, int n_in,
                              void* d_out, int out_size, void* d_ws, size_t ws_size,
                              hipStream_t stream) {
    const float* H  = (const float*)d_in[0];
    const float* G  = (const float*)d_in[1];
    const float* Sg = (const float*)d_in[2];
    const float* ew = (const float*)d_in[3];
    const int*   ed = (const int*)d_in[4];
    const int*   es = (const int*)d_in[5];

    const int B = 64;
    const int F = in_sizes[0] / B;        // 512
    const int S = in_sizes[2] / F;        // 8192
    const int E = in_sizes[3];            // 500000
    const int D = out_size / B;           // 1024
    float* out = (float*)d_out;

    // workspace layout (floats); every buffer fully written before read
    float* ws = (float*)d_ws;
    size_t off = 0;
    float* rinv    = ws + off; off += (size_t)S;                 // 8192
    float* Hs      = ws + off; off += (size_t)B * F;             // 32768
    float* gscale  = ws + off; off += 256;
    float* colsum  = ws + off; off += (size_t)D;
    float* W       = ws + off; off += (size_t)S * D;             // 8.39M
    float* Pt_part = ws + off; off += (size_t)KC1 * S * B;       // 1.05M
    float* pcs     = ws + off; off += (size_t)SCAT * D;          // 262144
    float* part    = ws + off; off += (size_t)NS2 * B * D;       // 4.19M

    hipMemsetAsync(W, 0, (size_t)S * D * sizeof(float), stream);

    k_norms<<<S + B, 256, 0, stream>>>(Sg, H, G, rinv, Hs, gscale, S, F, B);
    k_scatter<<<SCAT, 256, 0, stream>>>(ew, ed, es, W, pcs, E, D);
    k_colsum<<<(D + 255) / 256, 256, 0, stream>>>(pcs, colsum, D);
    dim3 g1(S / 32, KC1);
    k_gemm1<<<g1, 256, 0, stream>>>(Hs, Sg, rinv, Pt_part, S, F, F / KC1);
    dim3 g2(D / 64, NS2);
    k_gemm2<<<g2, 256, 0, stream>>>(Pt_part, W, part, S, D);
    k_epi<<<(B * D + 255) / 256, 256, 0, stream>>>(part, colsum, gscale, out, D, B);
}

// Round 7
// 155.099 us; speedup vs baseline: 2.4025x; 1.0618x over previous
//
#include <hip/hip_runtime.h>
#include <math.h>

#define EPS 1e-8f
#define KT 32
#define KC1 2
#define SCAT 512     // scatter blocks inside fused K1
#define NG1 512      // gemm1 blocks inside fused K1 (= (S/32)*KC1)
#define NS2 64       // gemm2 split-K chunks

// ---------------------------------------------------------------------------
// K0: norms + W-zero.
//  Blocks [0,S): rinv[s] = 1/(||S_s||+eps)  AND zero W row s (D floats).
//  Blocks [S, S+B): Hs[b,:] = H[b,:]/(||H_b||+eps), gscale[b]=0.005*||G_b||
// ---------------------------------------------------------------------------
__global__ void k_norms(const float* __restrict__ Sg, const float* __restrict__ Hg,
                        const float* __restrict__ Gg, float* __restrict__ rinv,
                        float* __restrict__ Hs, float* __restrict__ gscale,
                        float* __restrict__ W,
                        int Srows, int Fdim, int Bdim, int Dd) {
    __shared__ float wsum[4];
    __shared__ float wsum2[4];
    __shared__ float bc0;
    int row = blockIdx.x;
    int tid = threadIdx.x;
    int lane = tid & 63, wv = tid >> 6;

    if (row < Srows) {
        // zero W row (Dd floats, float4 stores)
        float4 z4 = {0.f, 0.f, 0.f, 0.f};
        float4* wp = (float4*)(W + (size_t)row * Dd);
        for (int i = tid; i < Dd / 4; i += 256) wp[i] = z4;

        const float* p = Sg + (size_t)row * Fdim;
        float acc = 0.f;
        for (int i = tid; i < Fdim; i += 256) { float v = p[i]; acc += v * v; }
        for (int off = 32; off > 0; off >>= 1) acc += __shfl_down(acc, off, 64);
        if (lane == 0) wsum[wv] = acc;
        __syncthreads();
        if (tid == 0) {
            float t = wsum[0] + wsum[1] + wsum[2] + wsum[3];
            rinv[row] = 1.0f / (sqrtf(t) + EPS);
        }
    } else {
        int b = row - Srows;
        if (b >= Bdim) return;
        const float* ph = Hg + (size_t)b * Fdim;
        const float* pg = Gg + (size_t)b * Fdim;
        float ah = 0.f, ag = 0.f;
        for (int i = tid; i < Fdim; i += 256) {
            float h = ph[i]; ah += h * h;
            float g = pg[i]; ag += g * g;
        }
        for (int off = 32; off > 0; off >>= 1) {
            ah += __shfl_down(ah, off, 64);
            ag += __shfl_down(ag, off, 64);
        }
        if (lane == 0) { wsum[wv] = ah; wsum2[wv] = ag; }
        __syncthreads();
        if (tid == 0) {
            float th = wsum[0] + wsum[1] + wsum[2] + wsum[3];
            float tg = wsum2[0] + wsum2[1] + wsum2[2] + wsum2[3];
            bc0 = 1.0f / (sqrtf(th) + EPS);
            gscale[b] = 0.005f * sqrtf(tg);
        }
        __syncthreads();
        float hn = bc0;
        float* dst = Hs + (size_t)b * Fdim;
        for (int i = tid; i < Fdim; i += 256) dst[i] = ph[i] * hn;
    }
}

// ---------------------------------------------------------------------------
// K1 fused: blocks [0,NG1) = GEMM1, blocks [NG1, NG1+SCAT) = edge scatter.
// Independent work co-resident per CU: VALU-bound gemm overlaps
// latency/atomic-bound scatter.
//
// GEMM1: Pt_part[kc][s][b] = rinv[s] * sum_{k in chunk kc} Hs[b,k]*Sg[s,k]
//   flat id: s0 = (id&255)*32, kc = id>>8. s-major float4 stores.
// Scatter: W[s,d] += w (global atomics); colsum partials -> pcs[sid][D].
// ---------------------------------------------------------------------------
__global__ __launch_bounds__(256) void k_g1scat(
        const float* __restrict__ Hs, const float* __restrict__ Sg,
        const float* __restrict__ rinv, float* __restrict__ Pt_part,
        const float* __restrict__ ew, const int* __restrict__ ed,
        const int* __restrict__ es, float* __restrict__ W,
        float* __restrict__ pcs,
        int Srows, int Fdim, int kchunk, int E, int Dd) {
    // union LDS: gemm1 needs 32*(68+36)=3328 floats; scatter needs Dd (1024)
    __shared__ float smem[KT * 104];
    #define LA(k, i) smem[(k) * 68 + (i)]
    #define LB(k, i) smem[KT * 68 + (k) * 36 + (i)]
    int id = blockIdx.x;
    int tid = threadIdx.x;

    if (id < NG1) {
        int tx = tid & 15;          // b: 4 each
        int ty = tid >> 4;          // s: 2 each
        int s0 = (id & 255) * 32;
        int kb = (id >> 8) * kchunk;

        float4 acc0 = {0.f, 0.f, 0.f, 0.f};
        float4 acc1 = {0.f, 0.f, 0.f, 0.f};

        for (int kt = 0; kt < kchunk; kt += KT) {
            #pragma unroll
            for (int i = 0; i < 8; i++) {
                int idx = tid + i * 256;
                int c = idx & 31, r = idx >> 5;
                LA(c, r) = Hs[(size_t)r * Fdim + kb + kt + c];
            }
            #pragma unroll
            for (int i = 0; i < 4; i++) {
                int idx = tid + i * 256;
                int c = idx & 31, r = idx >> 5;
                LB(c, r) = Sg[(size_t)(s0 + r) * Fdim + kb + kt + c];
            }
            __syncthreads();
            #pragma unroll
            for (int k = 0; k < KT; k++) {
                float4 hv = *(const float4*)&LA(k, tx * 4);
                float2 sv = *(const float2*)&LB(k, ty * 2);
                acc0.x += sv.x * hv.x; acc0.y += sv.x * hv.y;
                acc0.z += sv.x * hv.z; acc0.w += sv.x * hv.w;
                acc1.x += sv.y * hv.x; acc1.y += sv.y * hv.y;
                acc1.z += sv.y * hv.z; acc1.w += sv.y * hv.w;
            }
            __syncthreads();
        }
        int sa = s0 + ty * 2;
        float r0 = rinv[sa], r1 = rinv[sa + 1];
        float4 o0, o1;
        o0.x = acc0.x * r0; o0.y = acc0.y * r0; o0.z = acc0.z * r0; o0.w = acc0.w * r0;
        o1.x = acc1.x * r1; o1.y = acc1.y * r1; o1.z = acc1.z * r1; o1.w = acc1.w * r1;
        size_t base = (size_t)(id >> 8) * Srows;
        *(float4*)&Pt_part[(base + sa) * 64 + tx * 4]     = o0;
        *(float4*)&Pt_part[(base + sa + 1) * 64 + tx * 4] = o1;
    } else {
        int sid = id - NG1;
        float* bins = smem;                    // reuse LDS
        for (int i = tid; i < Dd; i += 256) bins[i] = 0.f;
        __syncthreads();
        int stride = SCAT * 256;
        for (int e = sid * 256 + tid; e < E; e += stride) {
            int s = es[e];
            int d = ed[e];
            float w = ew[e];
            atomicAdd(&W[(size_t)s * Dd + d], w);
            atomicAdd(&bins[d], w);
        }
        __syncthreads();
        float* dst = pcs + (size_t)sid * Dd;
        for (int i = tid; i < Dd; i += 256) dst[i] = bins[i];
    }
    #undef LA
    #undef LB
}

// ---------------------------------------------------------------------------
// K2: GEMM2  part[kc][b][d] = sum_{k in chunk kc} P'[b,k] * W[k,d]
// P' staged from s-major Pt_part, summing both split-K halves on the fly.
// Tile 64b x 64d, KT=32. Grid (D/64, NS2) = 1024 blocks = 4 waves/SIMD.
// Blocks (x<4, y==0) additionally reduce pcs -> colsum (ready pre-launch).
// ---------------------------------------------------------------------------
__global__ __launch_bounds__(256) void k_gemm2(
        const float* __restrict__ Pt_part, const float* __restrict__ W,
        float* __restrict__ part, const float* __restrict__ pcs,
        float* __restrict__ colsum, int Srows, int Dd) {
    __shared__ float lA[KT][64];    // [k][b]
    __shared__ float lB[KT][64];    // [k][d]
    int tid = threadIdx.x;
    int tx = tid & 15;   // d: 4 each
    int ty = tid >> 4;   // b: 4 each
    int d0 = blockIdx.x * 64;
    int kchunk = Srows / NS2;          // 128
    int kb = blockIdx.y * kchunk;
    size_t half = (size_t)Srows * 64;

    float4 acc[4];
    #pragma unroll
    for (int j = 0; j < 4; j++) { acc[j].x = acc[j].y = acc[j].z = acc[j].w = 0.f; }

    for (int kt = 0; kt < kchunk; kt += KT) {
        #pragma unroll
        for (int i = 0; i < 8; i++) {          // 32k x 64b
            int idx = tid + i * 256;
            int r = idx & 63, c = idx >> 6;    // r=b, c=k
            size_t src = (size_t)(kb + kt + c) * 64 + r;
            lA[c][r] = Pt_part[src] + Pt_part[half + src];
        }
        #pragma unroll
        for (int i = 0; i < 8; i++) {          // 32k x 64d
            int idx = tid + i * 256;
            int c = idx & 63, r = idx >> 6;    // c=d, r=k
            lB[r][c] = W[(size_t)(kb + kt + r) * Dd + d0 + c];
        }
        __syncthreads();
        #pragma unroll
        for (int k = 0; k < KT; k++) {
            float4 av = *(const float4*)&lA[k][ty * 4];
            float4 bv = *(const float4*)&lB[k][tx * 4];
            acc[0].x += av.x * bv.x; acc[0].y += av.x * bv.y; acc[0].z += av.x * bv.z; acc[0].w += av.x * bv.w;
            acc[1].x += av.y * bv.x; acc[1].y += av.y * bv.y; acc[1].z += av.y * bv.z; acc[1].w += av.y * bv.w;
            acc[2].x += av.z * bv.x; acc[2].y += av.z * bv.y; acc[2].z += av.z * bv.z; acc[2].w += av.z * bv.w;
            acc[3].x += av.w * bv.x; acc[3].y += av.w * bv.y; acc[3].z += av.w * bv.z; acc[3].w += av.w * bv.w;
        }
        __syncthreads();
    }
    #pragma unroll
    for (int j = 0; j < 4; j++) {
        int b = ty * 4 + j;
        *(float4*)&part[((size_t)blockIdx.y * 64 + b) * Dd + d0 + tx * 4] = acc[j];
    }

    // colsum side-job on 4 blocks (pcs complete before this kernel launched)
    if (blockIdx.y == 0 && blockIdx.x < 4) {
        int d = blockIdx.x * 256 + tid;
        float s = 0.f;
        #pragma unroll 8
        for (int c = 0; c < SCAT; c++) s += pcs[(size_t)c * Dd + d];
        colsum[d] = s;
    }
}

// ---------------------------------------------------------------------------
// K3: epilogue  out[b,d] = gscale[b] * (sum_kc part[kc][b][d] + colsum[d])
// ---------------------------------------------------------------------------
__global__ void k_epi(const float* __restrict__ part, const float* __restrict__ colsum,
                      const float* __restrict__ gscale, float* __restrict__ out,
                      int Dd, int Bdim) {
    int idx = blockIdx.x * 256 + threadIdx.x;
    if (idx >= Bdim * Dd) return;
    int b = idx / Dd;
    int d = idx - b * Dd;
    float s = 0.f;
    #pragma unroll 8
    for (int kc = 0; kc < NS2; kc++)
        s += part[((size_t)kc * Bdim + b) * Dd + d];
    out[idx] = gscale[b] * (s + colsum[d]);
}

extern "C" void kernel_launch(void* const* d_in, const int* in_sizes, int n_in,
                              void* d_out, int out_size, void* d_ws, size_t ws_size,
                              hipStream_t stream) {
    const float* H  = (const float*)d_in[0];
    const float* G  = (const float*)d_in[1];
    const float* Sg = (const float*)d_in[2];
    const float* ew = (const float*)d_in[3];
    const int*   ed = (const int*)d_in[4];
    const int*   es = (const int*)d_in[5];

    const int B = 64;
    const int F = in_sizes[0] / B;        // 512
    const int S = in_sizes[2] / F;        // 8192
    const int E = in_sizes[3];            // 500000
    const int D = out_size / B;           // 1024
    float* out = (float*)d_out;

    // workspace layout (floats); every buffer fully written before read
    float* ws = (float*)d_ws;
    size_t off = 0;
    float* rinv    = ws + off; off += (size_t)S;                 // 8192
    float* Hs      = ws + off; off += (size_t)B * F;             // 32768
    float* gscale  = ws + off; off += 256;
    float* colsum  = ws + off; off += (size_t)D;                 // 1024 (16B-align ok)
    float* W       = ws + off; off += (size_t)S * D;             // 8.39M
    float* Pt_part = ws + off; off += (size_t)KC1 * S * B;       // 1.05M
    float* pcs     = ws + off; off += (size_t)SCAT * D;          // 524288
    float* part    = ws + off; off += (size_t)NS2 * B * D;       // 4.19M

    // K0: norms + W-zero (S blocks zero one W row each)
    k_norms<<<S + B, 256, 0, stream>>>(Sg, H, G, rinv, Hs, gscale, W, S, F, B, D);
    // K1: gemm1 (512 blocks) || scatter (512 blocks)
    k_g1scat<<<NG1 + SCAT, 256, 0, stream>>>(Hs, Sg, rinv, Pt_part,
                                             ew, ed, es, W, pcs,
                                             S, F, F / KC1, E, D);
    // K2: gemm2 + colsum side-job
    dim3 g2(D / 64, NS2);
    k_gemm2<<<g2, 256, 0, stream>>>(Pt_part, W, part, pcs, colsum, S, D);
    // K3: epilogue
    k_epi<<<(B * D + 255) / 256, 256, 0, stream>>>(part, colsum, gscale, out, D, B);
}